// Round 5
// baseline (257.902 us; speedup 1.0000x reference)
//
#include <hip/hip_runtime.h>
#include <math.h>

#define TN 4096
#define HN 2048
#define NB 32
#define NCH 9
#define NCODES 512
#define CDIM 64
#define TAU 1e-3f

typedef _Float16 f16x8 __attribute__((ext_vector_type(8)));
typedef float f32x4 __attribute__((ext_vector_type(4)));

__device__ __forceinline__ float2 cmulf(float2 a, float2 b) {
    return make_float2(a.x * b.x - a.y * b.y, a.x * b.y + a.y * b.x);
}
__device__ __forceinline__ float2 f2add(float2 a, float2 b) {
    return make_float2(a.x + b.x, a.y + b.y);
}
__device__ __forceinline__ float2 f2sub(float2 a, float2 b) {
    return make_float2(a.x - b.x, a.y - b.y);
}

__device__ __forceinline__ unsigned long long packsi(float s, int i) {
    unsigned u = __float_as_uint(s);
    u = (u & 0x80000000u) ? ~u : (u | 0x80000000u);
    return ((unsigned long long)u << 32) | (unsigned)i;
}
__device__ __forceinline__ float unpacks(unsigned long long v) {
    unsigned u = (unsigned)(v >> 32);
    u = (u & 0x80000000u) ? (u & 0x7fffffffu) : ~u;
    return __uint_as_float(u);
}

// blocks 0..511: zero phases. block 512: codebook norms + f16 hi/lo split.
__global__ __launch_bounds__(256) void prep_kernel(const float* __restrict__ cb,
                                                   float* __restrict__ cn,
                                                   _Float16* __restrict__ cbh,
                                                   _Float16* __restrict__ cbl,
                                                   float* __restrict__ ph) {
    const int bid = blockIdx.x;
    const int tid = threadIdx.x;
    if (bid < 512) {
        ph[bid * 256 + tid] = 0.0f;
        return;
    }
    for (int i = tid; i < NCODES * CDIM; i += 256) {
        float c = cb[i];
        _Float16 h = (_Float16)c;
        cbh[i] = h;
        cbl[i] = (_Float16)(c - (float)h);
    }
    for (int k = tid; k < NCODES; k += 256) {
        const float4* c4 = (const float4*)(cb + (size_t)k * CDIM);
        float s = 0.0f;
        #pragma unroll
        for (int q = 0; q < 16; ++q) {
            float4 c = c4[q];
            s = fmaf(c.x, c.x, s);
            s = fmaf(c.y, c.y, s);
            s = fmaf(c.z, c.z, s);
            s = fmaf(c.w, c.w, s);
        }
        cn[k] = s;
    }
}

// Paired-row Hilbert (radix-4 Stockham, validated r3/r4). HT=1024: one
// butterfly per thread per stage; 80KB LDS -> 2 blocks/CU.
#define HT 1024
__global__ __launch_bounds__(HT) void hilbert_phase_kernel(
    const float* __restrict__ x, float* __restrict__ phases) {
    __shared__ float2 bufA[TN];
    __shared__ float2 bufB[TN];
    __shared__ float2 tw[HN];
    const int tid = threadIdx.x;
    const int row1 = 2 * blockIdx.x;
    const int row2 = row1 + 1;
    const int b1 = row1 / NCH;
    const int b2 = row2 / NCH;
    const float* xr1 = x + (size_t)row1 * TN;
    const float* xr2 = x + (size_t)row2 * TN;

    for (int i = tid; i < HN; i += HT) {
        float ang = -3.14159265358979323846f * ((float)i / (float)HN);
        float s, c;
        sincosf(ang, &s, &c);
        tw[i] = make_float2(c, s);
    }
    for (int i = tid; i < TN; i += HT) {
        bufA[i] = make_float2(xr1[i], xr2[i]);
    }
    __syncthreads();

    float2* src = bufA;
    float2* dst = bufB;
    for (int stage = 0; stage < 6; ++stage) {
        const int m = 1 << (2 * stage);
        for (int idx = tid; idx < 1024; idx += HT) {
            const int kk = idx & (m - 1);
            const int jm = idx - kk;
            float2 a0 = src[idx];
            float2 a1 = src[idx + 1024];
            float2 a2 = src[idx + 2048];
            float2 a3 = src[idx + 3072];
            float2 b0 = f2add(a0, a2);
            float2 b1 = f2add(a1, a3);
            float2 b2 = f2sub(a0, a2);
            float2 b3 = f2sub(a1, a3);
            float2 w1 = tw[jm];
            float2 w2 = tw[2 * jm];
            float2 w3 = cmulf(w1, w2);
            float2 y0 = f2add(b0, b1);
            float2 mi = make_float2(b2.x + b3.y, b2.y - b3.x);
            float2 pi_ = make_float2(b2.x - b3.y, b2.y + b3.x);
            dst[4 * jm + kk]         = y0;
            dst[4 * jm + kk + m]     = cmulf(mi, w1);
            dst[4 * jm + kk + 2 * m] = cmulf(f2sub(b0, b1), w2);
            dst[4 * jm + kk + 3 * m] = cmulf(pi_, w3);
        }
        __syncthreads();
        float2* t0 = src; src = dst; dst = t0;
    }
    const float inv = 1.0f / (float)TN;
    for (int i = tid; i < TN; i += HT) {
        float sc;
        if (i == 0 || i == HN) sc = inv;
        else if (i < HN) sc = 2.0f * inv;
        else sc = 0.0f;
        float2 v = src[i];
        v.x *= sc; v.y *= sc;
        src[i] = v;
    }
    __syncthreads();
    for (int stage = 0; stage < 6; ++stage) {
        const int m = 1 << (2 * stage);
        for (int idx = tid; idx < 1024; idx += HT) {
            const int kk = idx & (m - 1);
            const int jm = idx - kk;
            float2 a0 = src[idx];
            float2 a1 = src[idx + 1024];
            float2 a2 = src[idx + 2048];
            float2 a3 = src[idx + 3072];
            float2 b0 = f2add(a0, a2);
            float2 b1 = f2add(a1, a3);
            float2 b2 = f2sub(a0, a2);
            float2 b3 = f2sub(a1, a3);
            float2 w1 = tw[jm];      w1.y = -w1.y;
            float2 w2 = tw[2 * jm];  w2.y = -w2.y;
            float2 w3 = cmulf(w1, w2);
            float2 y0 = f2add(b0, b1);
            float2 pi_ = make_float2(b2.x - b3.y, b2.y + b3.x);
            float2 mi = make_float2(b2.x + b3.y, b2.y - b3.x);
            dst[4 * jm + kk]         = y0;
            dst[4 * jm + kk + m]     = cmulf(pi_, w1);
            dst[4 * jm + kk + 2 * m] = cmulf(f2sub(b0, b1), w2);
            dst[4 * jm + kk + 3 * m] = cmulf(mi, w3);
        }
        __syncthreads();
        float2* t0 = src; src = dst; dst = t0;
    }
    float* ph1 = phases + (size_t)b1 * TN;
    float* ph2 = phases + (size_t)b2 * TN;
    for (int i = tid; i < TN; i += HT) {
        float2 d = src[i];
        float x1v = xr1[i];
        float x2v = xr2[i];
        atomicAdd(&ph1[i], atan2f(d.y - x2v, x1v) * (1.0f / 9.0f));
        atomicAdd(&ph2[i], atan2f(x1v - d.x, x2v) * (1.0f / 9.0f));
    }
}

// vq via MFMA: 2048 blocks x 256 threads (4 waves). Block = 64 points; wave w
// owns points 16w..16w+15 (A rows), all 512 codes (B cols, 32 col-frags in
// 4 chunks of 8). f16 hi/lo split: dot = hh + hl + lh (err ~1e-5). Top-2
// tracked; rows with MFMA gap < TAU get exact f32 rescan.
__global__ __launch_bounds__(256) void vq_kernel(
    const float* __restrict__ imu,
    const float* __restrict__ Wm, const float* __restrict__ bm,
    const float* __restrict__ Wp, const float* __restrict__ bp,
    const float* __restrict__ cb,
    const float* __restrict__ cn,
    const _Float16* __restrict__ cbh,
    const _Float16* __restrict__ cbl,
    const float* __restrict__ phases,
    float* __restrict__ out_q, float* __restrict__ out_i) {
    __shared__ __align__(16) _Float16 sAh[64][64];   // 8 KB, 16B-block XOR swizzled
    __shared__ __align__(16) _Float16 sAl[64][64];   // 8 KB
    __shared__ __align__(16) float4 sF[64][16];      // 16 KB f32 copy (d4 XOR swizzled)
    __shared__ int s_idx[64];
    const int tid = threadIdx.x;
    const int lane = tid & 63;
    const int w = tid >> 6;
    const int p0 = blockIdx.x * 64;

    // ---- features: thread = (point=lane, dim-quarter=w) ----
    {
        const int pl = lane;
        const int p = p0 + pl;
        const int bb = p >> 12;
        const int tt = p & (TN - 1);
        float xc[9];
        #pragma unroll
        for (int c = 0; c < 9; ++c)
            xc[c] = imu[((size_t)(bb * 9 + c)) * TN + tt];
        float sp, cp;
        sincosf(phases[p], &sp, &cp);
        float v[16];
        if (w < 2) {
            #pragma unroll
            for (int jj = 0; jj < 16; ++jj) {
                const int j = 16 * w + jj;
                float a = bm[j];
                #pragma unroll
                for (int c = 0; c < 9; ++c) a = fmaf(Wm[j * 9 + c], xc[c], a);
                v[jj] = a;
            }
        } else {
            #pragma unroll
            for (int jj = 0; jj < 16; ++jj) {
                const int j = 16 * (w - 2) + jj;
                float a = bp[j];
                #pragma unroll
                for (int c = 0; c < 7; ++c) a = fmaf(Wp[j * 9 + c], xc[c], a);
                a = fmaf(Wp[j * 9 + 7], cp, a);
                a = fmaf(Wp[j * 9 + 8], sp, a);
                v[jj] = a;
            }
        }
        // f32 copy (swizzled float4 index), f16 hi/lo (swizzled 16B blocks)
        #pragma unroll
        for (int d4 = 0; d4 < 4; ++d4) {
            float4 fv = make_float4(v[4 * d4], v[4 * d4 + 1], v[4 * d4 + 2], v[4 * d4 + 3]);
            const int d4g = 4 * w + d4;
            sF[pl][d4g ^ (pl & 15)] = fv;
        }
        #pragma unroll
        for (int blk = 0; blk < 2; ++blk) {
            f16x8 h, l;
            #pragma unroll
            for (int j = 0; j < 8; ++j) {
                float val = v[8 * blk + j];
                _Float16 hh = (_Float16)val;
                h[j] = hh;
                l[j] = (_Float16)(val - (float)hh);
            }
            const int kb = 2 * w + blk;
            const int off = ((kb ^ (pl & 7)) << 3);
            *(f16x8*)&sAh[pl][off] = h;
            *(f16x8*)&sAl[pl][off] = l;
        }
    }
    __syncthreads();

    // ---- A fragments for this wave ----
    const int l15 = lane & 15;
    const int hi16 = lane >> 4;
    const int pi = 16 * w + l15;
    f16x8 aH[2], aL[2];
    #pragma unroll
    for (int s = 0; s < 2; ++s) {
        const int kb = 4 * s + hi16;
        const int off = ((kb ^ (pi & 7)) << 3);
        aH[s] = *(const f16x8*)&sAh[pi][off];
        aL[s] = *(const f16x8*)&sAl[pi][off];
    }

    // ---- 4 chunks x 8 col-frags ----
    float bbest[4] = {3.4e38f, 3.4e38f, 3.4e38f, 3.4e38f};
    float bsec[4]  = {3.4e38f, 3.4e38f, 3.4e38f, 3.4e38f};
    int bidx[4] = {0, 0, 0, 0};
    for (int ch = 0; ch < 4; ++ch) {
        f32x4 acc[8];
        float cnv[8];
        int col[8];
        #pragma unroll
        for (int c = 0; c < 8; ++c) {
            acc[c] = (f32x4){0.f, 0.f, 0.f, 0.f};
            col[c] = (ch * 8 + c) * 16 + l15;
            cnv[c] = cn[col[c]];
        }
        #pragma unroll
        for (int s = 0; s < 2; ++s) {
            f16x8 bH[8], bL[8];
            #pragma unroll
            for (int c = 0; c < 8; ++c) {
                const size_t base = (size_t)col[c] * CDIM + 32 * s + hi16 * 8;
                bH[c] = *(const f16x8*)(cbh + base);
                bL[c] = *(const f16x8*)(cbl + base);
            }
            #pragma unroll
            for (int c = 0; c < 8; ++c) {
                acc[c] = __builtin_amdgcn_mfma_f32_16x16x32_f16(aH[s], bH[c], acc[c], 0, 0, 0);
                acc[c] = __builtin_amdgcn_mfma_f32_16x16x32_f16(aH[s], bL[c], acc[c], 0, 0, 0);
                acc[c] = __builtin_amdgcn_mfma_f32_16x16x32_f16(aL[s], bH[c], acc[c], 0, 0, 0);
            }
        }
        #pragma unroll
        for (int c = 0; c < 8; ++c) {
            #pragma unroll
            for (int r = 0; r < 4; ++r) {
                float sc = fmaf(-2.0f, acc[c][r], cnv[c]);
                bool lt = sc < bbest[r];
                float cand = lt ? bbest[r] : sc;
                bsec[r] = fminf(bsec[r], cand);
                bbest[r] = fminf(bbest[r], sc);
                bidx[r] = lt ? col[c] : bidx[r];
            }
        }
    }

    // ---- cross-lane top-2 merge within each 16-lane group ----
    unsigned long long pb[4], ps[4];
    #pragma unroll
    for (int r = 0; r < 4; ++r) {
        pb[r] = packsi(bbest[r], bidx[r]);
        ps[r] = packsi(bsec[r], 0);
    }
    #pragma unroll
    for (int m = 1; m <= 8; m <<= 1) {
        #pragma unroll
        for (int r = 0; r < 4; ++r) {
            unsigned long long ob = __shfl_xor(pb[r], m, 64);
            unsigned long long os = __shfl_xor(ps[r], m, 64);
            unsigned long long mx = pb[r] > ob ? pb[r] : ob;
            unsigned long long mn = ps[r] < os ? ps[r] : os;
            ps[r] = mx < mn ? mx : mn;
            pb[r] = pb[r] < ob ? pb[r] : ob;
        }
    }
    if (l15 == 0) {
        #pragma unroll
        for (int r = 0; r < 4; ++r) {
            const int row = 16 * w + 4 * hi16 + r;
            const int bi = (int)(pb[r] & 0xFFFFFFFFu);
            s_idx[row] = bi;
            out_i[p0 + row] = (float)bi;
        }
    }
    float gap[4];
    #pragma unroll
    for (int r = 0; r < 4; ++r) gap[r] = unpacks(ps[r]) - unpacks(pb[r]);

    // ---- exact f32 rescan of near-tie rows (rare, wave-uniform branch) ----
    for (int rr = 0; rr < 16; ++rr) {
        float g = __shfl(gap[rr & 3], (rr >> 2) * 16, 64);
        if (g < TAU) {
            const int prow = 16 * w + rr;
            unsigned long long pbest = ~0ull;
            for (int cc = 0; cc < 8; ++cc) {
                const int kk = lane * 8 + cc;
                const float4* crow = (const float4*)(cb + (size_t)kk * CDIM);
                float a0 = 0.f, a1 = 0.f, a2 = 0.f, a3 = 0.f;
                #pragma unroll
                for (int d4 = 0; d4 < 16; ++d4) {
                    float4 fv = sF[prow][d4 ^ (prow & 15)];
                    float4 cv = crow[d4];
                    a0 = fmaf(fv.x, cv.x, a0);
                    a1 = fmaf(fv.y, cv.y, a1);
                    a2 = fmaf(fv.z, cv.z, a2);
                    a3 = fmaf(fv.w, cv.w, a3);
                }
                float sc = fmaf(-2.0f, (a0 + a1) + (a2 + a3), cn[kk]);
                unsigned long long pk = packsi(sc, kk);
                pbest = pk < pbest ? pk : pbest;
            }
            #pragma unroll
            for (int m = 1; m <= 32; m <<= 1) {
                unsigned long long o = __shfl_xor(pbest, m, 64);
                pbest = o < pbest ? o : pbest;
            }
            if (lane == 0) {
                const int bi = (int)(pbest & 0xFFFFFFFFu);
                s_idx[prow] = bi;
                out_i[p0 + prow] = (float)bi;
            }
        }
    }
    __syncthreads();

    // ---- cooperative coalesced gather of quantized rows ----
    float4* oq = (float4*)out_q;
    const float4* c4g = (const float4*)cb;
    for (int i = tid; i < 64 * 16; i += 256) {
        const int pt = i >> 4;
        const int q = i & 15;
        oq[(size_t)(p0 + pt) * 16 + q] = c4g[(size_t)s_idx[pt] * 16 + q];
    }
}

extern "C" void kernel_launch(void* const* d_in, const int* in_sizes, int n_in,
                              void* d_out, int out_size, void* d_ws, size_t ws_size,
                              hipStream_t stream) {
    const float* imu = (const float*)d_in[0];
    const float* Wm  = (const float*)d_in[1];
    const float* bm  = (const float*)d_in[2];
    const float* Wp  = (const float*)d_in[3];
    const float* bp  = (const float*)d_in[4];
    const float* cb  = (const float*)d_in[5];

    float* out_q = (float*)d_out;                          // (32,4096,64)
    float* out_i = out_q + (size_t)NB * TN * CDIM;         // (32,4096) as float
    float* out_p = out_i + (size_t)NB * TN;                // (32,4096) phases

    float* cn       = (float*)d_ws;                         // 512 f32
    _Float16* cbh   = (_Float16*)((char*)d_ws + 2048);      // 64 KB
    _Float16* cbl   = (_Float16*)((char*)d_ws + 2048 + 65536);

    prep_kernel<<<513, 256, 0, stream>>>(cb, cn, cbh, cbl, out_p);
    hilbert_phase_kernel<<<NB * NCH / 2, HT, 0, stream>>>(imu, out_p);
    vq_kernel<<<(NB * TN) / 64, 256, 0, stream>>>(imu, Wm, bm, Wp, bp, cb,
                                                  cn, cbh, cbl, out_p, out_q, out_i);
}